// Round 7
// baseline (525.024 us; speedup 1.0000x reference)
//
#include <hip/hip_runtime.h>
#include <hip/hip_bf16.h>
#include <stdint.h>

#define TSEQ 2048
#define NH   16
#define DKH  64
#define DM   1024

typedef __attribute__((ext_vector_type(8))) __bf16 bf16x8;
typedef __attribute__((ext_vector_type(4))) float floatx4;
typedef __attribute__((address_space(1))) void gvoid_t;
typedef __attribute__((address_space(3))) void lvoid_t;

#if __has_builtin(__builtin_amdgcn_exp2f)
#define EXP2F(x) __builtin_amdgcn_exp2f(x)
#else
#define EXP2F(x) exp2f(x)
#endif

__device__ __forceinline__ unsigned short f2bf(float f) {
  union { float f; unsigned u; } v; v.f = f;
  return (unsigned short)((v.u + 0x7fffu + ((v.u >> 16) & 1u)) >> 16);
}
__device__ __forceinline__ unsigned pack2bf(float a, float b) {
  float2 f; f.x = a; f.y = b;
  __hip_bfloat162 h = __float22bfloat162_rn(f);
  unsigned u; __builtin_memcpy(&u, &h, 4); return u;
}
__device__ __forceinline__ bf16x8 cvt8(float4 a, float4 b) {
  unsigned u[4] = {pack2bf(a.x, a.y), pack2bf(a.z, a.w), pack2bf(b.x, b.y), pack2bf(b.z, b.w)};
  bf16x8 r; __builtin_memcpy(&r, u, 16); return r;
}
__device__ __forceinline__ bf16x8 ld_frag(const void* p) {
  bf16x8 r; __builtin_memcpy(&r, p, 16); return r;
}
__device__ __forceinline__ void gl2lds16(const void* g, void* l) {
  __builtin_amdgcn_global_load_lds((gvoid_t*)(uintptr_t)g,
                                   (lvoid_t*)(unsigned)(uintptr_t)l, 16, 0, 0);
}

// ---------------- fused transpose of 4 weights: fp32 in -> bf16 out[n][k] ----------------
__global__ void wt_transpose4(const float* __restrict__ w0, const float* __restrict__ w1,
                              const float* __restrict__ w2, const float* __restrict__ w3,
                              unsigned short* __restrict__ out) {
  __shared__ unsigned short tile[32][33];
  const float* srcs[4] = {w0, w1, w2, w3};
  const float* in = srcs[blockIdx.z];
  unsigned short* o = out + (size_t)blockIdx.z * DM * DM;
  int bx = blockIdx.x * 32, by = blockIdx.y * 32;
  int x = threadIdx.x;
  for (int j = threadIdx.y; j < 32; j += 8)
    tile[j][x] = f2bf(in[(size_t)(by + j) * DM + bx + x]);
  __syncthreads();
  for (int j = threadIdx.y; j < 32; j += 8)
    o[(size_t)(bx + j) * DM + by + x] = tile[x][j];
}

// ---------------- fused QKV projection GEMM ----------------
// grid (M/128, 8, 3): x = m-tile (XCD affinity: id%8 == x%8 -> one A-tile per XCD),
// z selects {q,k,v}. A fp32 -> bf16 at frag read. out bf16:
//   z<2: [nb,H,T,DKH]; z==2: [nb,H,DKH,T].
// LDS swizzle: A fp32 [128][32]: chunk c at phys c^(row&7); B bf16 [128][32]: c^((row>>1)&3).
__global__ __launch_bounds__(256, 4) void gemm_qkv(
    const float* __restrict__ q, const float* __restrict__ k, const float* __restrict__ v,
    const unsigned short* __restrict__ WTs,
    const float* __restrict__ bq, const float* __restrict__ bk, const float* __restrict__ bv,
    unsigned short* __restrict__ outBase, size_t outStride) {
  __shared__ __align__(16) unsigned char Asm[16384];
  __shared__ __align__(16) unsigned char Bsm[8192];
  const int tid = threadIdx.x;
  const int wave = tid >> 6, lane = tid & 63;
  const int quad = lane >> 4, l16 = lane & 15;
  const int wm = wave & 1, wn = wave >> 1;
  const int z = blockIdx.z;
  const int m0 = blockIdx.x * 128, n0 = blockIdx.y * 128;

  const float* As[3] = {q, k, v};
  const float* Bs[3] = {bq, bk, bv};
  const float* A32 = As[z];
  const float* bias = Bs[z];
  const unsigned short* WT = WTs + (size_t)z * DM * DM;
  unsigned short* out = outBase + (size_t)z * outStride;

  const float* gA[4]; const unsigned short* gB[2];
  char *ldsA[4], *ldsB[2];
#pragma unroll
  for (int it = 0; it < 4; it++) {
    int cl = (wave * 4 + it) * 64 + lane;
    int row = cl >> 3, phys = cl & 7;
    int cG = phys ^ (row & 7);
    gA[it] = A32 + (size_t)(m0 + row) * DM + cG * 4;
    ldsA[it] = (char*)Asm + cl * 16;
  }
#pragma unroll
  for (int it = 0; it < 2; it++) {
    int cl = (wave * 2 + it) * 64 + lane;
    int row = cl >> 2, phys = cl & 3;
    int cG = phys ^ ((row >> 1) & 3);
    gB[it] = WT + (size_t)(n0 + row) * DM + cG * 8;
    ldsB[it] = (char*)Bsm + cl * 16;
  }

  int offA0[4], offA1[4], offB[4];
#pragma unroll
  for (int mt = 0; mt < 4; mt++) {
    int row = wm * 64 + mt * 16 + l16;
    offA0[mt] = row * 128 + ((2 * quad) ^ (row & 7)) * 16;
    offA1[mt] = row * 128 + ((2 * quad + 1) ^ (row & 7)) * 16;
  }
#pragma unroll
  for (int nt = 0; nt < 4; nt++) {
    int row = wn * 64 + nt * 16 + l16;
    offB[nt] = row * 64 + (quad ^ ((row >> 1) & 3)) * 16;
  }

  floatx4 acc[4][4];
#pragma unroll
  for (int i = 0; i < 4; i++)
#pragma unroll
    for (int j = 0; j < 4; j++) acc[i][j] = (floatx4){0.f, 0.f, 0.f, 0.f};

  for (int k0 = 0; k0 < DM; k0 += 32) {
#pragma unroll
    for (int it = 0; it < 4; it++) { gl2lds16(gA[it], ldsA[it]); gA[it] += 32; }
#pragma unroll
    for (int it = 0; it < 2; it++) { gl2lds16(gB[it], ldsB[it]); gB[it] += 32; }
    __syncthreads();

    bf16x8 af[4], bfr[4];
#pragma unroll
    for (int mt = 0; mt < 4; mt++) {
      float4 fa, fb;
      __builtin_memcpy(&fa, Asm + offA0[mt], 16);
      __builtin_memcpy(&fb, Asm + offA1[mt], 16);
      af[mt] = cvt8(fa, fb);
    }
#pragma unroll
    for (int nt = 0; nt < 4; nt++)
      bfr[nt] = ld_frag(Bsm + offB[nt]);
#pragma unroll
    for (int mt = 0; mt < 4; mt++)
#pragma unroll
      for (int nt = 0; nt < 4; nt++)
        acc[mt][nt] = __builtin_amdgcn_mfma_f32_16x16x32_bf16(af[mt], bfr[nt], acc[mt][nt], 0, 0, 0);
    __syncthreads();
  }

#pragma unroll
  for (int nt = 0; nt < 4; nt++) {
    int n = n0 + wn * 64 + nt * 16 + l16;
    float bv2 = bias[n];
#pragma unroll
    for (int mt = 0; mt < 4; mt++) {
#pragma unroll
      for (int r = 0; r < 4; r++) {
        int m = m0 + wm * 64 + mt * 16 + quad * 4 + r;
        unsigned short o = f2bf(acc[mt][nt][r] + bv2);
        int b = m >> 11, t = m & 2047, h = n >> 6, dk = n & 63;
        if (z == 2)
          out[(size_t)(((b * NH + h) * DKH) + dk) * TSEQ + t] = o;
        else
          out[(size_t)(((b * NH + h) * TSEQ) + t) * DKH + dk] = o;
      }
    }
  }
}

// ---------------- output GEMM: fp32 out = ctx(bf16) * WoT + bo ----------------
// grid (M/128, 8): x = m-tile (XCD affinity).
__global__ __launch_bounds__(256, 4) void gemm_out(
    const unsigned short* __restrict__ A16,
    const unsigned short* __restrict__ WT,
    const float* __restrict__ bias,
    float* __restrict__ out) {
  __shared__ __align__(16) unsigned char Asm[8192];
  __shared__ __align__(16) unsigned char Bsm[8192];
  const int tid = threadIdx.x;
  const int wave = tid >> 6, lane = tid & 63;
  const int quad = lane >> 4, l16 = lane & 15;
  const int wm = wave & 1, wn = wave >> 1;
  const int m0 = blockIdx.x * 128, n0 = blockIdx.y * 128;

  const unsigned short* gA[2]; const unsigned short* gB[2];
  char *ldsA[2], *ldsB[2];
#pragma unroll
  for (int it = 0; it < 2; it++) {
    int cl = (wave * 2 + it) * 64 + lane;
    int row = cl >> 2, phys = cl & 3;
    int cG = phys ^ ((row >> 1) & 3);
    gA[it] = A16 + (size_t)(m0 + row) * DM + cG * 8;
    gB[it] = WT + (size_t)(n0 + row) * DM + cG * 8;
    ldsA[it] = (char*)Asm + cl * 16;
    ldsB[it] = (char*)Bsm + cl * 16;
  }
  int offA[4], offB[4];
#pragma unroll
  for (int mt = 0; mt < 4; mt++) {
    int row = wm * 64 + mt * 16 + l16;
    offA[mt] = row * 64 + (quad ^ ((row >> 1) & 3)) * 16;
  }
#pragma unroll
  for (int nt = 0; nt < 4; nt++) {
    int row = wn * 64 + nt * 16 + l16;
    offB[nt] = row * 64 + (quad ^ ((row >> 1) & 3)) * 16;
  }

  floatx4 acc[4][4];
#pragma unroll
  for (int i = 0; i < 4; i++)
#pragma unroll
    for (int j = 0; j < 4; j++) acc[i][j] = (floatx4){0.f, 0.f, 0.f, 0.f};

  for (int k0 = 0; k0 < DM; k0 += 32) {
#pragma unroll
    for (int it = 0; it < 2; it++) {
      gl2lds16(gA[it], ldsA[it]); gA[it] += 32;
      gl2lds16(gB[it], ldsB[it]); gB[it] += 32;
    }
    __syncthreads();
    bf16x8 af[4], bfr[4];
#pragma unroll
    for (int mt = 0; mt < 4; mt++) af[mt] = ld_frag(Asm + offA[mt]);
#pragma unroll
    for (int nt = 0; nt < 4; nt++) bfr[nt] = ld_frag(Bsm + offB[nt]);
#pragma unroll
    for (int mt = 0; mt < 4; mt++)
#pragma unroll
      for (int nt = 0; nt < 4; nt++)
        acc[mt][nt] = __builtin_amdgcn_mfma_f32_16x16x32_bf16(af[mt], bfr[nt], acc[mt][nt], 0, 0, 0);
    __syncthreads();
  }

#pragma unroll
  for (int nt = 0; nt < 4; nt++) {
    int n = n0 + wn * 64 + nt * 16 + l16;
    float bv2 = bias[n];
#pragma unroll
    for (int mt = 0; mt < 4; mt++)
#pragma unroll
      for (int r = 0; r < 4; r++) {
        int m = m0 + wm * 64 + mt * 16 + quad * 4 + r;
        out[(size_t)m * DM + n] = acc[mt][nt][r] + bv2;
      }
  }
}

// ---------------- flash attention (S^T, swizzled LDS, reg-pipelined K/V) ----------------
// grid (nb*16, 16): x = bh (XCD affinity: one head's K/V stays on one XCD), y = q-tile.
__global__ __launch_bounds__(256, 4) void flash_attn(
    const unsigned short* __restrict__ Q,
    const unsigned short* __restrict__ K,
    const unsigned short* __restrict__ VT,
    unsigned short* __restrict__ ctx) {
  __shared__ __align__(16) unsigned short QP[128 * 64];  // Q tile, then per-wave P
  __shared__ __align__(16) unsigned short Ksm[64 * 64];
  __shared__ __align__(16) unsigned short Vsm[64 * 64];

  const int tid = threadIdx.x;
  const int wave = tid >> 6, lane = tid & 63;
  const int quad = lane >> 4, l16 = lane & 15;
  const int bh = blockIdx.x;
  const int t0 = blockIdx.y * 128;
  const unsigned short* Qg = Q + (size_t)bh * TSEQ * DKH;
  const unsigned short* Kg = K + (size_t)bh * TSEQ * DKH;
  const unsigned short* Vg = VT + (size_t)bh * DKH * TSEQ;

  // stage Q via DMA (one-shot)
#pragma unroll
  for (int it = 0; it < 4; it++) {
    int cl = (wave * 4 + it) * 64 + lane;
    int row = cl >> 3, phys = cl & 7;
    int cG = phys ^ (row & 7);
    gl2lds16(Qg + (size_t)(t0 + row) * DKH + cG * 8, (char*)QP + cl * 16);
  }
  // K/V reg-pipeline descriptors
  const unsigned short* gK[2]; const unsigned short* gV[2];
  int ldsOff[2];
  uint4 rK[2], rV[2];
#pragma unroll
  for (int it = 0; it < 2; it++) {
    int cl = (wave * 2 + it) * 64 + lane;
    int row = cl >> 3, phys = cl & 7;
    int cG = phys ^ (row & 7);
    gK[it] = Kg + (size_t)row * DKH + cG * 8;
    gV[it] = Vg + (size_t)row * TSEQ + cG * 8;
    ldsOff[it] = cl * 16;
  }
  // prefetch tile 0
#pragma unroll
  for (int it = 0; it < 2; it++) {
    __builtin_memcpy(&rK[it], gK[it], 16); gK[it] += 64 * DKH;
    __builtin_memcpy(&rV[it], gV[it], 16); gV[it] += 64;
  }
  __syncthreads();  // Q visible

  const int sw = l16 & 7;
  int foff[2];
#pragma unroll
  for (int ks = 0; ks < 2; ks++)
    foff[ks] = l16 * 128 + ((ks * 4 + quad) ^ sw) * 16;

  bf16x8 qf[2][2];
#pragma unroll
  for (int qt = 0; qt < 2; qt++)
#pragma unroll
    for (int ks = 0; ks < 2; ks++)
      qf[qt][ks] = ld_frag((char*)QP + (wave * 32 + qt * 16) * 128 + foff[ks]);

  char* Pw = (char*)QP + wave * 4096;

  floatx4 O[2][4];
  float mrun[2], lrun[2];
#pragma unroll
  for (int qt = 0; qt < 2; qt++) {
#pragma unroll
    for (int dt = 0; dt < 4; dt++) O[qt][dt] = (floatx4){0.f, 0.f, 0.f, 0.f};
    mrun[qt] = -1e30f; lrun[qt] = 0.f;
  }
  const float sl = 0.125f * 1.44269504f;

  for (int j0 = 0; j0 < TSEQ; j0 += 64) {
    // commit staged regs to LDS
#pragma unroll
    for (int it = 0; it < 2; it++) {
      __builtin_memcpy((char*)Ksm + ldsOff[it], &rK[it], 16);
      __builtin_memcpy((char*)Vsm + ldsOff[it], &rV[it], 16);
    }
    __syncthreads();
    // prefetch next tile: latency overlaps the whole compute section below
    if (j0 + 64 < TSEQ) {
#pragma unroll
      for (int it = 0; it < 2; it++) {
        __builtin_memcpy(&rK[it], gK[it], 16); gK[it] += 64 * DKH;
        __builtin_memcpy(&rV[it], gV[it], 16); gV[it] += 64;
      }
    }

    // S^T = K Q^T
    bf16x8 kf[4][2];
#pragma unroll
    for (int kt = 0; kt < 4; kt++)
#pragma unroll
      for (int ks = 0; ks < 2; ks++)
        kf[kt][ks] = ld_frag((char*)Ksm + kt * 16 * 128 + foff[ks]);
    floatx4 st[4][2];
#pragma unroll
    for (int kt = 0; kt < 4; kt++)
#pragma unroll
      for (int qt = 0; qt < 2; qt++) {
        floatx4 a = (floatx4){0.f, 0.f, 0.f, 0.f};
        a = __builtin_amdgcn_mfma_f32_16x16x32_bf16(kf[kt][0], qf[qt][0], a, 0, 0, 0);
        a = __builtin_amdgcn_mfma_f32_16x16x32_bf16(kf[kt][1], qf[qt][1], a, 0, 0, 0);
        st[kt][qt] = a;
      }

    // online softmax + P write (swizzled, 8B packed)
    float aO[2][4];
#pragma unroll
    for (int qt = 0; qt < 2; qt++) {
      float mx = -3e38f;
#pragma unroll
      for (int kt = 0; kt < 4; kt++)
#pragma unroll
        for (int r = 0; r < 4; r++) mx = fmaxf(mx, st[kt][qt][r]);
      mx = fmaxf(mx, __shfl_xor(mx, 16, 64));
      mx = fmaxf(mx, __shfl_xor(mx, 32, 64));
      mx *= sl;
      float mnew = fmaxf(mrun[qt], mx);
      float alpha = EXP2F(mrun[qt] - mnew);
      mrun[qt] = mnew;
      float rs = 0.f;
#pragma unroll
      for (int kt = 0; kt < 4; kt++) {
        float p0 = EXP2F(st[kt][qt][0] * sl - mnew);
        float p1 = EXP2F(st[kt][qt][1] * sl - mnew);
        float p2 = EXP2F(st[kt][qt][2] * sl - mnew);
        float p3 = EXP2F(st[kt][qt][3] * sl - mnew);
        rs += (p0 + p1) + (p2 + p3);
        uint2 u; u.x = pack2bf(p0, p1); u.y = pack2bf(p2, p3);
        int physC = (2 * kt + (quad >> 1)) ^ sw;
        __builtin_memcpy(Pw + (qt * 16 + l16) * 128 + physC * 16 + (quad & 1) * 8, &u, 8);
      }
      rs += __shfl_xor(rs, 16, 64);
      rs += __shfl_xor(rs, 32, 64);
      lrun[qt] = lrun[qt] * alpha + rs;
#pragma unroll
      for (int r = 0; r < 4; r++)
        aO[qt][r] = __shfl(alpha, quad * 20 + r, 64);
    }

#pragma unroll
    for (int qt = 0; qt < 2; qt++)
#pragma unroll
      for (int dt = 0; dt < 4; dt++)
#pragma unroll
        for (int r = 0; r < 4; r++) O[qt][dt][r] *= aO[qt][r];

    // O += P V
    bf16x8 vf[4][2];
#pragma unroll
    for (int dt = 0; dt < 4; dt++)
#pragma unroll
      for (int ks = 0; ks < 2; ks++)
        vf[dt][ks] = ld_frag((char*)Vsm + dt * 16 * 128 + foff[ks]);
#pragma unroll
    for (int qt = 0; qt < 2; qt++) {
      bf16x8 pf[2];
#pragma unroll
      for (int ks = 0; ks < 2; ks++)
        pf[ks] = ld_frag(Pw + qt * 16 * 128 + foff[ks]);
#pragma unroll
      for (int dt = 0; dt < 4; dt++) {
        O[qt][dt] = __builtin_amdgcn_mfma_f32_16x16x32_bf16(pf[0], vf[dt][0], O[qt][dt], 0, 0, 0);
        O[qt][dt] = __builtin_amdgcn_mfma_f32_16x16x32_bf16(pf[1], vf[dt][1], O[qt][dt], 0, 0, 0);
      }
    }
    __syncthreads();
  }

  int b = bh >> 4, h = bh & 15;
#pragma unroll
  for (int qt = 0; qt < 2; qt++) {
#pragma unroll
    for (int r = 0; r < 4; r++) {
      float linv = 1.0f / __shfl(lrun[qt], quad * 20 + r, 64);
      int t = t0 + wave * 32 + qt * 16 + quad * 4 + r;
#pragma unroll
      for (int dt = 0; dt < 4; dt++) {
        int dk = dt * 16 + l16;
        ctx[((size_t)b * TSEQ + t) * DM + h * DKH + dk] = f2bf(O[qt][dt][r] * linv);
      }
    }
  }
}

extern "C" void kernel_launch(void* const* d_in, const int* in_sizes, int n_in,
                              void* d_out, int out_size, void* d_ws, size_t ws_size,
                              hipStream_t stream) {
  const float* q  = (const float*)d_in[0];
  const float* k  = (const float*)d_in[1];
  const float* v  = (const float*)d_in[2];
  const float* Wq = (const float*)d_in[3];
  const float* bq = (const float*)d_in[4];
  const float* Wk = (const float*)d_in[5];
  const float* bk = (const float*)d_in[6];
  const float* Wv = (const float*)d_in[7];
  const float* bv = (const float*)d_in[8];
  const float* Wo = (const float*)d_in[9];
  const float* bo = (const float*)d_in[10];

  const size_t MiB = 1024 * 1024;
  int nb;
  if      (ws_size >= 72 * MiB) nb = 4;
  else if (ws_size >= 40 * MiB) nb = 2;
  else                          nb = 1;
  const int passes = 4 / nb;

  unsigned char* ws = (unsigned char*)d_ws;
  unsigned short* WTs = (unsigned short*)ws;  // WqT,WkT,WvT,WoT contiguous
  unsigned short* WoT = WTs + (size_t)3 * DM * DM;
  const size_t tensorE = (size_t)nb * TSEQ * DM;  // elems per projected tensor
  unsigned short* Qp = (unsigned short*)(ws + 8 * MiB);
  unsigned short* Kp = Qp + tensorE;
  unsigned short* Vp = Kp + tensorE;
  unsigned short* Cx = Vp + tensorE;

  wt_transpose4<<<dim3(32, 32, 4), dim3(32, 8), 0, stream>>>(Wq, Wk, Wv, Wo, WTs);

  for (int p = 0; p < passes; p++) {
    const float* qp = q + (size_t)p * tensorE;
    const float* kp = k + (size_t)p * tensorE;
    const float* vp = v + (size_t)p * tensorE;
    float* outp = (float*)d_out + (size_t)p * tensorE;

    gemm_qkv<<<dim3(nb * 16, 8, 3), 256, 0, stream>>>(qp, kp, vp, WTs, bq, bk, bv, Qp, tensorE);
    flash_attn<<<dim3(nb * 16, 16), 256, 0, stream>>>(Qp, Kp, Vp, Cx);
    gemm_out<<<dim3(nb * 16, 8), 256, 0, stream>>>(Cx, WoT, bo, outp);
  }
}

// Round 8
// 398.601 us; speedup vs baseline: 1.3172x; 1.3172x over previous
//
#include <hip/hip_runtime.h>
#include <hip/hip_bf16.h>
#include <stdint.h>

#define TSEQ 2048
#define NH   16
#define DKH  64
#define DM   1024

typedef __attribute__((ext_vector_type(8))) __bf16 bf16x8;
typedef __attribute__((ext_vector_type(4))) float floatx4;
typedef __attribute__((address_space(1))) void gvoid_t;
typedef __attribute__((address_space(3))) void lvoid_t;

#if __has_builtin(__builtin_amdgcn_exp2f)
#define EXP2F(x) __builtin_amdgcn_exp2f(x)
#else
#define EXP2F(x) exp2f(x)
#endif

__device__ __forceinline__ unsigned short f2bf(float f) {
  union { float f; unsigned u; } v; v.f = f;
  return (unsigned short)((v.u + 0x7fffu + ((v.u >> 16) & 1u)) >> 16);
}
__device__ __forceinline__ unsigned pack2bf(float a, float b) {
  float2 f; f.x = a; f.y = b;
  __hip_bfloat162 h = __float22bfloat162_rn(f);
  unsigned u; __builtin_memcpy(&u, &h, 4); return u;
}
__device__ __forceinline__ bf16x8 cvt8(float4 a, float4 b) {
  unsigned u[4] = {pack2bf(a.x, a.y), pack2bf(a.z, a.w), pack2bf(b.x, b.y), pack2bf(b.z, b.w)};
  bf16x8 r; __builtin_memcpy(&r, u, 16); return r;
}
__device__ __forceinline__ bf16x8 ld_frag(const void* p) {
  bf16x8 r; __builtin_memcpy(&r, p, 16); return r;
}
__device__ __forceinline__ void gl2lds16(const void* g, void* l) {
  __builtin_amdgcn_global_load_lds((gvoid_t*)(uintptr_t)g,
                                   (lvoid_t*)(unsigned)(uintptr_t)l, 16, 0, 0);
}

// ---------------- fused transpose of 4 weights: fp32 in -> bf16 out[n][k] ----------------
__global__ void wt_transpose4(const float* __restrict__ w0, const float* __restrict__ w1,
                              const float* __restrict__ w2, const float* __restrict__ w3,
                              unsigned short* __restrict__ out) {
  __shared__ unsigned short tile[32][33];
  const float* srcs[4] = {w0, w1, w2, w3};
  const float* in = srcs[blockIdx.z];
  unsigned short* o = out + (size_t)blockIdx.z * DM * DM;
  int bx = blockIdx.x * 32, by = blockIdx.y * 32;
  int x = threadIdx.x;
  for (int j = threadIdx.y; j < 32; j += 8)
    tile[j][x] = f2bf(in[(size_t)(by + j) * DM + bx + x]);
  __syncthreads();
  for (int j = threadIdx.y; j < 32; j += 8)
    o[(size_t)(bx + j) * DM + by + x] = tile[x][j];
}

// ---------------- fused QKV projection GEMM (double-buffered DMA) ----------------
// grid (M/128, 8, 3): x = m-tile (XCD affinity), z selects {q,k,v}.
// LDS: A fp32 [2][128][32] chunk c at phys c^(row&7); B bf16 [2][128][32] c^((row>>1)&3).
__global__ __launch_bounds__(256, 3) void gemm_qkv(
    const float* __restrict__ q, const float* __restrict__ k, const float* __restrict__ v,
    const unsigned short* __restrict__ WTs,
    const float* __restrict__ bq, const float* __restrict__ bk, const float* __restrict__ bv,
    unsigned short* __restrict__ outBase, size_t outStride) {
  __shared__ __align__(16) unsigned char Asm[2 * 16384];
  __shared__ __align__(16) unsigned char Bsm[2 * 8192];
  const int tid = threadIdx.x;
  const int wave = tid >> 6, lane = tid & 63;
  const int quad = lane >> 4, l16 = lane & 15;
  const int wm = wave & 1, wn = wave >> 1;
  const int z = blockIdx.z;
  const int m0 = blockIdx.x * 128, n0 = blockIdx.y * 128;

  const float* As[3] = {q, k, v};
  const float* Bs[3] = {bq, bk, bv};
  const float* A32 = As[z];
  const float* bias = Bs[z];
  const unsigned short* WT = WTs + (size_t)z * DM * DM;
  unsigned short* out = outBase + (size_t)z * outStride;

  const float* gA[4]; const unsigned short* gB[2];
  int aoff[4], boff[2];
#pragma unroll
  for (int it = 0; it < 4; it++) {
    int cl = (wave * 4 + it) * 64 + lane;
    int row = cl >> 3, phys = cl & 7;
    int cG = phys ^ (row & 7);
    gA[it] = A32 + (size_t)(m0 + row) * DM + cG * 4;
    aoff[it] = cl * 16;
  }
#pragma unroll
  for (int it = 0; it < 2; it++) {
    int cl = (wave * 2 + it) * 64 + lane;
    int row = cl >> 2, phys = cl & 3;
    int cG = phys ^ ((row >> 1) & 3);
    gB[it] = WT + (size_t)(n0 + row) * DM + cG * 8;
    boff[it] = cl * 16;
  }

  int offA0[4], offA1[4], offB[4];
#pragma unroll
  for (int mt = 0; mt < 4; mt++) {
    int row = wm * 64 + mt * 16 + l16;
    offA0[mt] = row * 128 + ((2 * quad) ^ (row & 7)) * 16;
    offA1[mt] = row * 128 + ((2 * quad + 1) ^ (row & 7)) * 16;
  }
#pragma unroll
  for (int nt = 0; nt < 4; nt++) {
    int row = wn * 64 + nt * 16 + l16;
    offB[nt] = row * 64 + (quad ^ ((row >> 1) & 3)) * 16;
  }

  floatx4 acc[4][4];
#pragma unroll
  for (int i = 0; i < 4; i++)
#pragma unroll
    for (int j = 0; j < 4; j++) acc[i][j] = (floatx4){0.f, 0.f, 0.f, 0.f};

  // prologue: stage tile 0 into buffer 0
#pragma unroll
  for (int it = 0; it < 4; it++) { gl2lds16(gA[it], (char*)Asm + aoff[it]); gA[it] += 32; }
#pragma unroll
  for (int it = 0; it < 2; it++) { gl2lds16(gB[it], (char*)Bsm + boff[it]); gB[it] += 32; }
  __syncthreads();

  int cur = 0;
  for (int k0 = 0; k0 < DM; k0 += 32) {
    int nxt = cur ^ 1;
    if (k0 + 32 < DM) {  // prefetch next tile into the other buffer
#pragma unroll
      for (int it = 0; it < 4; it++) { gl2lds16(gA[it], (char*)Asm + nxt * 16384 + aoff[it]); gA[it] += 32; }
#pragma unroll
      for (int it = 0; it < 2; it++) { gl2lds16(gB[it], (char*)Bsm + nxt * 8192 + boff[it]); gB[it] += 32; }
    }
    const char* aB = (const char*)Asm + cur * 16384;
    const char* bB = (const char*)Bsm + cur * 8192;
    bf16x8 af[4], bfr[4];
#pragma unroll
    for (int mt = 0; mt < 4; mt++) {
      float4 fa, fb;
      __builtin_memcpy(&fa, aB + offA0[mt], 16);
      __builtin_memcpy(&fb, aB + offA1[mt], 16);
      af[mt] = cvt8(fa, fb);
    }
#pragma unroll
    for (int nt = 0; nt < 4; nt++)
      bfr[nt] = ld_frag(bB + offB[nt]);
#pragma unroll
    for (int mt = 0; mt < 4; mt++)
#pragma unroll
      for (int nt = 0; nt < 4; nt++)
        acc[mt][nt] = __builtin_amdgcn_mfma_f32_16x16x32_bf16(af[mt], bfr[nt], acc[mt][nt], 0, 0, 0);
    if (k0 + 32 < DM) __syncthreads();
    cur = nxt;
  }

#pragma unroll
  for (int nt = 0; nt < 4; nt++) {
    int n = n0 + wn * 64 + nt * 16 + l16;
    float bv2 = bias[n];
#pragma unroll
    for (int mt = 0; mt < 4; mt++) {
#pragma unroll
      for (int r = 0; r < 4; r++) {
        int m = m0 + wm * 64 + mt * 16 + quad * 4 + r;
        unsigned short o = f2bf(acc[mt][nt][r] + bv2);
        int b = m >> 11, t = m & 2047, h = n >> 6, dk = n & 63;
        if (z == 2)
          out[(size_t)(((b * NH + h) * DKH) + dk) * TSEQ + t] = o;
        else
          out[(size_t)(((b * NH + h) * TSEQ) + t) * DKH + dk] = o;
      }
    }
  }
}

// ---------------- output GEMM (double-buffered DMA): fp32 out = ctx(bf16)*WoT + bo ----------------
__global__ __launch_bounds__(256, 4) void gemm_out(
    const unsigned short* __restrict__ A16,
    const unsigned short* __restrict__ WT,
    const float* __restrict__ bias,
    float* __restrict__ out) {
  __shared__ __align__(16) unsigned char Asm[2 * 8192];
  __shared__ __align__(16) unsigned char Bsm[2 * 8192];
  const int tid = threadIdx.x;
  const int wave = tid >> 6, lane = tid & 63;
  const int quad = lane >> 4, l16 = lane & 15;
  const int wm = wave & 1, wn = wave >> 1;
  const int m0 = blockIdx.x * 128, n0 = blockIdx.y * 128;

  const unsigned short* gA[2]; const unsigned short* gB[2];
  int soff[2];
#pragma unroll
  for (int it = 0; it < 2; it++) {
    int cl = (wave * 2 + it) * 64 + lane;
    int row = cl >> 2, phys = cl & 3;
    int cG = phys ^ ((row >> 1) & 3);
    gA[it] = A16 + (size_t)(m0 + row) * DM + cG * 8;
    gB[it] = WT + (size_t)(n0 + row) * DM + cG * 8;
    soff[it] = cl * 16;
  }
  int offA[4], offB[4];
#pragma unroll
  for (int mt = 0; mt < 4; mt++) {
    int row = wm * 64 + mt * 16 + l16;
    offA[mt] = row * 64 + (quad ^ ((row >> 1) & 3)) * 16;
  }
#pragma unroll
  for (int nt = 0; nt < 4; nt++) {
    int row = wn * 64 + nt * 16 + l16;
    offB[nt] = row * 64 + (quad ^ ((row >> 1) & 3)) * 16;
  }

  floatx4 acc[4][4];
#pragma unroll
  for (int i = 0; i < 4; i++)
#pragma unroll
    for (int j = 0; j < 4; j++) acc[i][j] = (floatx4){0.f, 0.f, 0.f, 0.f};

#pragma unroll
  for (int it = 0; it < 2; it++) {
    gl2lds16(gA[it], (char*)Asm + soff[it]); gA[it] += 32;
    gl2lds16(gB[it], (char*)Bsm + soff[it]); gB[it] += 32;
  }
  __syncthreads();

  int cur = 0;
  for (int k0 = 0; k0 < DM; k0 += 32) {
    int nxt = cur ^ 1;
    if (k0 + 32 < DM) {
#pragma unroll
      for (int it = 0; it < 2; it++) {
        gl2lds16(gA[it], (char*)Asm + nxt * 8192 + soff[it]); gA[it] += 32;
        gl2lds16(gB[it], (char*)Bsm + nxt * 8192 + soff[it]); gB[it] += 32;
      }
    }
    const char* aB = (const char*)Asm + cur * 8192;
    const char* bB = (const char*)Bsm + cur * 8192;
    bf16x8 af[4], bfr[4];
#pragma unroll
    for (int mt = 0; mt < 4; mt++) af[mt] = ld_frag(aB + offA[mt]);
#pragma unroll
    for (int nt = 0; nt < 4; nt++) bfr[nt] = ld_frag(bB + offB[nt]);
#pragma unroll
    for (int mt = 0; mt < 4; mt++)
#pragma unroll
      for (int nt = 0; nt < 4; nt++)
        acc[mt][nt] = __builtin_amdgcn_mfma_f32_16x16x32_bf16(af[mt], bfr[nt], acc[mt][nt], 0, 0, 0);
    if (k0 + 32 < DM) __syncthreads();
    cur = nxt;
  }

#pragma unroll
  for (int nt = 0; nt < 4; nt++) {
    int n = n0 + wn * 64 + nt * 16 + l16;
    float bv2 = bias[n];
#pragma unroll
    for (int mt = 0; mt < 4; mt++)
#pragma unroll
      for (int r = 0; r < 4; r++) {
        int m = m0 + wm * 64 + mt * 16 + quad * 4 + r;
        out[(size_t)m * DM + n] = acc[mt][nt][r] + bv2;
      }
  }
}

// ---------------- flash attention (S^T, swizzled LDS, double-buffered K/V DMA) ----------------
// grid (nb*16, 16): x = bh (XCD affinity), y = q-tile.
__global__ __launch_bounds__(256, 3) void flash_attn(
    const unsigned short* __restrict__ Q,
    const unsigned short* __restrict__ K,
    const unsigned short* __restrict__ VT,
    unsigned short* __restrict__ ctx) {
  __shared__ __align__(16) unsigned short QP[128 * 64];      // Q tile, then per-wave P
  __shared__ __align__(16) unsigned short Ksm[2 * 64 * 64];  // double-buffered
  __shared__ __align__(16) unsigned short Vsm[2 * 64 * 64];

  const int tid = threadIdx.x;
  const int wave = tid >> 6, lane = tid & 63;
  const int quad = lane >> 4, l16 = lane & 15;
  const int bh = blockIdx.x;
  const int t0 = blockIdx.y * 128;
  const unsigned short* Qg = Q + (size_t)bh * TSEQ * DKH;
  const unsigned short* Kg = K + (size_t)bh * TSEQ * DKH;
  const unsigned short* Vg = VT + (size_t)bh * DKH * TSEQ;

  // stage Q via DMA (one-shot)
#pragma unroll
  for (int it = 0; it < 4; it++) {
    int cl = (wave * 4 + it) * 64 + lane;
    int row = cl >> 3, phys = cl & 7;
    int cG = phys ^ (row & 7);
    gl2lds16(Qg + (size_t)(t0 + row) * DKH + cG * 8, (char*)QP + cl * 16);
  }
  // K/V DMA descriptors
  const unsigned short* gK[2]; const unsigned short* gV[2];
  int soff[2];
#pragma unroll
  for (int it = 0; it < 2; it++) {
    int cl = (wave * 2 + it) * 64 + lane;
    int row = cl >> 3, phys = cl & 7;
    int cG = phys ^ (row & 7);
    gK[it] = Kg + (size_t)row * DKH + cG * 8;
    gV[it] = Vg + (size_t)row * TSEQ + cG * 8;
    soff[it] = cl * 16;
  }
  // prologue: stage K/V tile 0 into buffer 0
#pragma unroll
  for (int it = 0; it < 2; it++) {
    gl2lds16(gK[it], (char*)Ksm + soff[it]); gK[it] += 64 * DKH;
    gl2lds16(gV[it], (char*)Vsm + soff[it]); gV[it] += 64;
  }
  __syncthreads();  // Q + tile0 visible

  const int sw = l16 & 7;
  int foff[2];
#pragma unroll
  for (int ks = 0; ks < 2; ks++)
    foff[ks] = l16 * 128 + ((ks * 4 + quad) ^ sw) * 16;

  bf16x8 qf[2][2];
#pragma unroll
  for (int qt = 0; qt < 2; qt++)
#pragma unroll
    for (int ks = 0; ks < 2; ks++)
      qf[qt][ks] = ld_frag((char*)QP + (wave * 32 + qt * 16) * 128 + foff[ks]);

  char* Pw = (char*)QP + wave * 4096;

  floatx4 O[2][4];
  float mrun[2], lrun[2];
#pragma unroll
  for (int qt = 0; qt < 2; qt++) {
#pragma unroll
    for (int dt = 0; dt < 4; dt++) O[qt][dt] = (floatx4){0.f, 0.f, 0.f, 0.f};
    mrun[qt] = -1e30f; lrun[qt] = 0.f;
  }
  const float sl = 0.125f * 1.44269504f;

  int cur = 0;
  for (int j0 = 0; j0 < TSEQ; j0 += 64) {
    int nxt = cur ^ 1;
    if (j0 + 64 < TSEQ) {  // prefetch next K/V tile into the other buffer
#pragma unroll
      for (int it = 0; it < 2; it++) {
        gl2lds16(gK[it], (char*)Ksm + nxt * 8192 + soff[it]); gK[it] += 64 * DKH;
        gl2lds16(gV[it], (char*)Vsm + nxt * 8192 + soff[it]); gV[it] += 64;
      }
    }
    const char* kB = (const char*)Ksm + cur * 8192;
    const char* vB = (const char*)Vsm + cur * 8192;

    // S^T = K Q^T
    bf16x8 kf[4][2];
#pragma unroll
    for (int kt = 0; kt < 4; kt++)
#pragma unroll
      for (int ks = 0; ks < 2; ks++)
        kf[kt][ks] = ld_frag(kB + kt * 16 * 128 + foff[ks]);
    floatx4 st[4][2];
#pragma unroll
    for (int kt = 0; kt < 4; kt++)
#pragma unroll
      for (int qt = 0; qt < 2; qt++) {
        floatx4 a = (floatx4){0.f, 0.f, 0.f, 0.f};
        a = __builtin_amdgcn_mfma_f32_16x16x32_bf16(kf[kt][0], qf[qt][0], a, 0, 0, 0);
        a = __builtin_amdgcn_mfma_f32_16x16x32_bf16(kf[kt][1], qf[qt][1], a, 0, 0, 0);
        st[kt][qt] = a;
      }

    // online softmax + P write (swizzled, 8B packed)
    float aO[2][4];
#pragma unroll
    for (int qt = 0; qt < 2; qt++) {
      float mx = -3e38f;
#pragma unroll
      for (int kt = 0; kt < 4; kt++)
#pragma unroll
        for (int r = 0; r < 4; r++) mx = fmaxf(mx, st[kt][qt][r]);
      mx = fmaxf(mx, __shfl_xor(mx, 16, 64));
      mx = fmaxf(mx, __shfl_xor(mx, 32, 64));
      mx *= sl;
      float mnew = fmaxf(mrun[qt], mx);
      float alpha = EXP2F(mrun[qt] - mnew);
      mrun[qt] = mnew;
      float rs = 0.f;
#pragma unroll
      for (int kt = 0; kt < 4; kt++) {
        float p0 = EXP2F(st[kt][qt][0] * sl - mnew);
        float p1 = EXP2F(st[kt][qt][1] * sl - mnew);
        float p2 = EXP2F(st[kt][qt][2] * sl - mnew);
        float p3 = EXP2F(st[kt][qt][3] * sl - mnew);
        rs += (p0 + p1) + (p2 + p3);
        uint2 u; u.x = pack2bf(p0, p1); u.y = pack2bf(p2, p3);
        int physC = (2 * kt + (quad >> 1)) ^ sw;
        __builtin_memcpy(Pw + (qt * 16 + l16) * 128 + physC * 16 + (quad & 1) * 8, &u, 8);
      }
      rs += __shfl_xor(rs, 16, 64);
      rs += __shfl_xor(rs, 32, 64);
      lrun[qt] = lrun[qt] * alpha + rs;
#pragma unroll
      for (int r = 0; r < 4; r++)
        aO[qt][r] = __shfl(alpha, quad * 20 + r, 64);
    }

#pragma unroll
    for (int qt = 0; qt < 2; qt++)
#pragma unroll
      for (int dt = 0; dt < 4; dt++)
#pragma unroll
        for (int r = 0; r < 4; r++) O[qt][dt][r] *= aO[qt][r];

    // O += P V
    bf16x8 vf[4][2];
#pragma unroll
    for (int dt = 0; dt < 4; dt++)
#pragma unroll
      for (int ks = 0; ks < 2; ks++)
        vf[dt][ks] = ld_frag(vB + dt * 16 * 128 + foff[ks]);
#pragma unroll
    for (int qt = 0; qt < 2; qt++) {
      bf16x8 pf[2];
#pragma unroll
      for (int ks = 0; ks < 2; ks++)
        pf[ks] = ld_frag(Pw + qt * 16 * 128 + foff[ks]);
#pragma unroll
      for (int dt = 0; dt < 4; dt++) {
        O[qt][dt] = __builtin_amdgcn_mfma_f32_16x16x32_bf16(pf[0], vf[dt][0], O[qt][dt], 0, 0, 0);
        O[qt][dt] = __builtin_amdgcn_mfma_f32_16x16x32_bf16(pf[1], vf[dt][1], O[qt][dt], 0, 0, 0);
      }
    }
    if (j0 + 64 < TSEQ) __syncthreads();
    cur = nxt;
  }

  int b = bh >> 4, h = bh & 15;
#pragma unroll
  for (int qt = 0; qt < 2; qt++) {
#pragma unroll
    for (int r = 0; r < 4; r++) {
      float linv = 1.0f / __shfl(lrun[qt], quad * 20 + r, 64);
      int t = t0 + wave * 32 + qt * 16 + quad * 4 + r;
#pragma unroll
      for (int dt = 0; dt < 4; dt++) {
        int dk = dt * 16 + l16;
        ctx[((size_t)b * TSEQ + t) * DM + h * DKH + dk] = f2bf(O[qt][dt][r] * linv);
      }
    }
  }
}

extern "C" void kernel_launch(void* const* d_in, const int* in_sizes, int n_in,
                              void* d_out, int out_size, void* d_ws, size_t ws_size,
                              hipStream_t stream) {
  const float* q  = (const float*)d_in[0];
  const float* k  = (const float*)d_in[1];
  const float* v  = (const float*)d_in[2];
  const float* Wq = (const float*)d_in[3];
  const float* bq = (const float*)d_in[4];
  const float* Wk = (const float*)d_in[5];
  const float* bk = (const float*)d_in[6];
  const float* Wv = (const float*)d_in[7];
  const float* bv = (const float*)d_in[8];
  const float* Wo = (const float*)d_in[9];
  const float* bo = (const float*)d_in[10];

  const size_t MiB = 1024 * 1024;
  int nb;
  if      (ws_size >= 72 * MiB) nb = 4;
  else if (ws_size >= 40 * MiB) nb = 2;
  else                          nb = 1;
  const int passes = 4 / nb;

  unsigned char* ws = (unsigned char*)d_ws;
  unsigned short* WTs = (unsigned short*)ws;  // WqT,WkT,WvT,WoT contiguous
  unsigned short* WoT = WTs + (size_t)3 * DM * DM;
  const size_t tensorE = (size_t)nb * TSEQ * DM;
  unsigned short* Qp = (unsigned short*)(ws + 8 * MiB);
  unsigned short* Kp = Qp + tensorE;
  unsigned short* Vp = Kp + tensorE;
  unsigned short* Cx = Vp + tensorE;

  wt_transpose4<<<dim3(32, 32, 4), dim3(32, 8), 0, stream>>>(Wq, Wk, Wv, Wo, WTs);

  for (int p = 0; p < passes; p++) {
    const float* qp = q + (size_t)p * tensorE;
    const float* kp = k + (size_t)p * tensorE;
    const float* vp = v + (size_t)p * tensorE;
    float* outp = (float*)d_out + (size_t)p * tensorE;

    gemm_qkv<<<dim3(nb * 16, 8, 3), 256, 0, stream>>>(qp, kp, vp, WTs, bq, bk, bv, Qp, tensorE);
    flash_attn<<<dim3(nb * 16, 16), 256, 0, stream>>>(Qp, Kp, Vp, Cx);
    gemm_out<<<dim3(nb * 16, 8), 256, 0, stream>>>(Cx, WoT, bo, outp);
  }
}